// Round 9
// baseline (168.679 us; speedup 1.0000x reference)
//
#include <hip/hip_runtime.h>

typedef __bf16 bf16x8 __attribute__((ext_vector_type(8)));
typedef short  s16x8  __attribute__((ext_vector_type(8)));
typedef float  f32x4  __attribute__((ext_vector_type(4)));

#define DEVINL __device__ __forceinline__

DEVINL unsigned short f2bf(float f) {
  unsigned int u = __builtin_bit_cast(unsigned int, f);
  u += 0x7fffu + ((u >> 16) & 1u);   // round-to-nearest-even
  return (unsigned short)(u >> 16);
}

DEVINL void async16(const void* g, void* l) {
  __builtin_amdgcn_global_load_lds(
      (const __attribute__((address_space(1))) unsigned int*)g,
      (__attribute__((address_space(3))) unsigned int*)l, 16, 0, 0);
}

// ---------------- conversion kernels ----------------

__global__ void cvt_f32_bf16(const float* __restrict__ in,
                             unsigned short* __restrict__ out, int n4) {
  int i = blockIdx.x * blockDim.x + threadIdx.x;
  int stride = gridDim.x * blockDim.x;
  for (; i < n4; i += stride) {
    float4 v = ((const float4*)in)[i];
    ushort4 o;
    o.x = f2bf(v.x); o.y = f2bf(v.y); o.z = f2bf(v.z); o.w = f2bf(v.w);
    ((ushort4*)out)[i] = o;
  }
}

// in: [R][C] fp32  ->  out: [C][R] bf16
__global__ void transpose_cvt(const float* __restrict__ in,
                              unsigned short* __restrict__ out, int R, int C) {
  __shared__ unsigned short tile[32][33];
  int bc = blockIdx.x * 32, br = blockIdx.y * 32;
  int tx = threadIdx.x & 31, ty = threadIdx.x >> 5;
#pragma unroll
  for (int i = 0; i < 32; i += 8)
    tile[ty + i][tx] = f2bf(in[(size_t)(br + ty + i) * C + (bc + tx)]);
  __syncthreads();
#pragma unroll
  for (int i = 0; i < 32; i += 8)
    out[(size_t)(bc + ty + i) * R + (br + tx)] = tile[tx][ty + i];
}

__global__ void qconst(const float* __restrict__ theta,
                       const float* __restrict__ wre,
                       const float* __restrict__ wim,
                       float* __restrict__ c1, int n) {
  int i = blockIdx.x * blockDim.x + threadIdx.x;
  if (i < n) {
    float t = theta[i];
    c1[i] = (cosf(t) * wre[i] + sinf(t) * wim[i]) * wim[i] * 0.1f;
  }
}

// ---------- 8-phase GEMM (m201 schedule) + persistent REPS tiles ----------
// BM x 256 tile, BK=64, 8 waves (2M x 4N). Phase/vmcnt ledger as R8 (verified
// 3 rounds, 0 bank conflicts, no spill). New in R9:
//  - REPS>1: one block processes REPS adjacent tn tiles (shared A-panel).
//    Rep boundary: next-rep tile0 (A+B) + tile1 B staged BEFORE the epilogue
//    (their ~900cy latency hides under it), then vmcnt(0)+BAR publishes.
//    WAR-safe: tile NT-1 reads are drained by its per-phase lgkmcnt(0)s and
//    the final BAR precedes the boundary stages.
//  - FUSED epilogue: per-wave 2KB LDS scratch (above the 128KB buffers).
//    acc -> ds_write_b16 (swizzled) -> 2x ds_read_b128 -> 2x 16B global
//    stores; 4 consecutive lanes emit 128B contiguous => full-line writes
//    (fixes the 135MB half-line write inflation seen in R8 counters).

template <int BM, int NT, int REPS, bool FUSED>
__global__ __launch_bounds__(512, 2) void gemm8(
    const unsigned short* __restrict__ A,
    const unsigned short* __restrict__ Bt,
    const float* __restrict__ bias,
    const float* __restrict__ theta,
    const float* __restrict__ c1,
    void* __restrict__ Cout,
    int N, int nTilesN) {
  constexpr int K      = NT * 64;
  constexpr int WROWS  = BM / 2;
  constexpr int M_REP  = WROWS / 16;    // 8 (BM=256) or 4 (BM=128)
  constexpr int MH     = M_REP / 2;
  constexpr int ABYTES = BM * 128;
  constexpr int AH     = ABYTES / 2;
  constexpr int AL     = AH / 8192;     // gload_lds per A unit (2 / 1)
  constexpr int BUFSZ  = ABYTES + 32768;
  constexpr int LDSSZ  = 2 * BUFSZ + (FUSED ? 16384 : 0);
  static_assert(AL == 2 || AL == 1, "geometry");

  __shared__ __align__(16) char lds[LDSSZ];

  // bijective XCD swizzle (grid % 8 == 0 for both instantiations)
  int nwg = gridDim.x;
  int wg = blockIdx.x;
  int sw = (wg & 7) * (nwg >> 3) + (wg >> 3);
  int rowBase = (sw / nTilesN) * BM;
  int colBase = (sw % nTilesN) * (256 * REPS);

  const int t = threadIdx.x;
  const int lane = t & 63;
  const int wid = t >> 6;
  const int wr = wid >> 2, wc = wid & 3;   // 2M x 4N waves
  const int lr = lane & 15;
  const int lg = lane >> 4;                // 0..3
  const int r7 = lane & 7;

  // staging source (pre-swizzled global address, linear LDS dest)
  const int srow = t >> 3;                              // 0..63
  const int scolB = ((t & 7) * 16) ^ ((srow & 7) << 4);
  const unsigned short* aSrcB = A  + (size_t)(rowBase + srow) * K + (scolB >> 1);
  const unsigned short* bSrcB = Bt + (size_t)(colBase + srow) * K + (scolB >> 1);

  // swizzled ds_read bases (bytes)
  const int aRd = (wr * WROWS + lr) * 128 + ((lg ^ r7) << 4);
  const int bRd = ABYTES + (wc * 64 + lr) * 128 + ((lg ^ r7) << 4);

#define STAGE_AU(S, U, P) do {                                              \
    _Pragma("unroll") for (int j = 0; j < AL; ++j)                          \
      async16(aSrcB + ((size_t)((U) * WROWS + j * 64) * K + (size_t)(S) * 64),\
              &lds[(P) * BUFSZ + (U) * AH + j * 8192 + t * 16]);            \
  } while (0)
#define STAGE_BU(SRC, S, U, P) do {                                         \
    _Pragma("unroll") for (int j = 0; j < 2; ++j)                           \
      async16((SRC) + ((size_t)((U) * 128 + j * 64) * K + (size_t)(S) * 64),\
              &lds[(P) * BUFSZ + ABYTES + (U) * 16384 + j * 8192 + t * 16]);\
  } while (0)

#define LOAD_A(MHh, P)                                                      \
  _Pragma("unroll") for (int mi = 0; mi < MH; ++mi)                         \
  _Pragma("unroll") for (int ks = 0; ks < 2; ++ks)                          \
    a[mi][ks] = __builtin_bit_cast(bf16x8, *(const s16x8*)&lds[             \
        (P) * BUFSZ + ((aRd + ((MHh) * MH + mi) * 2048) ^ (ks << 6))])
#define LOAD_B(NHh, P)                                                      \
  _Pragma("unroll") for (int nn = 0; nn < 2; ++nn)                          \
  _Pragma("unroll") for (int ks = 0; ks < 2; ++ks)                          \
    b[(NHh) * 2 + nn][ks] = __builtin_bit_cast(bf16x8, *(const s16x8*)&lds[ \
        (P) * BUFSZ + ((bRd + ((NHh) * 2 + nn) * 2048) ^ (ks << 6))])

#define QUAD(MHh, NHh)                                                      \
  __builtin_amdgcn_s_setprio(1);                                            \
  _Pragma("unroll") for (int mi = 0; mi < MH; ++mi)                         \
  _Pragma("unroll") for (int nn = 0; nn < 2; ++nn)                          \
  _Pragma("unroll") for (int ks = 0; ks < 2; ++ks)                          \
    acc[(MHh) * MH + mi][(NHh) * 2 + nn] =                                  \
        __builtin_amdgcn_mfma_f32_16x16x32_bf16(                            \
            a[mi][ks], b[(NHh) * 2 + nn][ks],                               \
            acc[(MHh) * MH + mi][(NHh) * 2 + nn], 0, 0, 0);                 \
  __builtin_amdgcn_s_setprio(0)

#define BAR() __builtin_amdgcn_s_barrier()
#define LG0() asm volatile("s_waitcnt lgkmcnt(0)" ::: "memory")

#define TILE(T, P) do {                                                     \
    LOAD_A(0, P); LOAD_B(0, P);                                             \
    if ((T) + 1 < NT) STAGE_AU((T) + 1, 0, (P) ^ 1);                        \
    if (MH == 4) asm volatile("s_waitcnt lgkmcnt(8)" ::: "memory");         \
    BAR(); LG0(); QUAD(0, 0); BAR();                                        \
    LOAD_B(1, P);                                                           \
    if ((T) + 1 < NT) STAGE_AU((T) + 1, 1, (P) ^ 1);                        \
    BAR(); LG0(); QUAD(0, 1); BAR();                                        \
    LOAD_A(1, P);                                                           \
    if ((T) + 2 < NT) STAGE_BU(bSrcR, (T) + 2, 0, P);                       \
    BAR(); LG0(); QUAD(1, 1); BAR();                                        \
    if ((T) + 2 < NT) STAGE_BU(bSrcR, (T) + 2, 1, P);                       \
    BAR(); QUAD(1, 0);                                                      \
    if ((T) + 2 < NT) {                                                     \
      asm volatile("s_waitcnt vmcnt(4)" ::: "memory");                      \
    } else if ((T) + 1 < NT) {                                              \
      asm volatile("s_waitcnt vmcnt(0)" ::: "memory");                      \
    }                                                                       \
    BAR();                                                                  \
  } while (0)

  // prologue (rep 0): tile0 A+B, tile1 B
  STAGE_AU(0, 0, 0); STAGE_AU(0, 1, 0);
  STAGE_BU(bSrcB, 0, 0, 0); STAGE_BU(bSrcB, 0, 1, 0);
  STAGE_BU(bSrcB, 1, 0, 1); STAGE_BU(bSrcB, 1, 1, 1);
  asm volatile("s_waitcnt vmcnt(4)" ::: "memory");
  BAR();

  for (int rep = 0; rep < REPS; ++rep) {
    const unsigned short* bSrcR = bSrcB + (size_t)rep * 256 * K;
    f32x4 acc[M_REP][4] = {};
    bf16x8 a[MH][2], b[4][2];

    for (int T = 0; T < NT; T += 2) {   // NT even (16, 64)
      TILE(T, 0);
      TILE(T + 1, 1);
    }

    // boundary staging for next rep: issued BEFORE the epilogue so its
    // latency hides under it. Regions free: all tile reads drained above.
    if (rep + 1 < REPS) {
      const unsigned short* bSrcN = bSrcB + (size_t)(rep + 1) * 256 * K;
      STAGE_AU(0, 0, 0); STAGE_AU(0, 1, 0);
      STAGE_BU(bSrcN, 0, 0, 0); STAGE_BU(bSrcN, 0, 1, 0);
      STAGE_BU(bSrcN, 1, 0, 1); STAGE_BU(bSrcN, 1, 1, 1);
    }

    // ---- epilogue ----
    const int colR = colBase + rep * 256;
    const int ocol0 = colR + wc * 64 + lr;
    if constexpr (FUSED) {
      float bvv[4], thv[4], ccv[4];
#pragma unroll
      for (int ni = 0; ni < 4; ++ni) {
        int n = ocol0 + ni * 16;
        bvv[ni] = bias[n]; thv[ni] = theta[n]; ccv[ni] = c1[n];
      }
      // per-wave 2KB scratch above the staging buffers
      const int SB = 2 * BUFSZ + wid * 2048;
      const int srw = lane >> 2;                 // 0..15 scratch row
      const int sbyte = (lane & 3) * 32;
      const size_t growB = (size_t)(rowBase + wr * WROWS) * N;
      unsigned short* outp = (unsigned short*)Cout;
#pragma unroll
      for (int mi = 0; mi < M_REP; ++mi) {
#pragma unroll
        for (int ni = 0; ni < 4; ++ni) {
#pragma unroll
          for (int r = 0; r < 4; ++r) {
            int row16 = lg * 4 + r;
            float h = acc[mi][ni][r] + bvv[ni];
            float q = h + ccv[ni] * __sinf(thv[ni] + 0.1f * h);
            unsigned short v = f2bf(fmaxf(q, 0.f));
            int ad = SB + row16 * 128 +
                     (((ni * 16 + lr) * 2) ^ ((row16 & 7) << 4));
            *(unsigned short*)&lds[ad] = v;
          }
        }
        s16x8 w0 = *(const s16x8*)&lds[SB + srw * 128 +
                                       ((sbyte) ^ ((srw & 7) << 4))];
        s16x8 w1 = *(const s16x8*)&lds[SB + srw * 128 +
                                       ((sbyte + 16) ^ ((srw & 7) << 4))];
        unsigned short* dst = outp + growB + (size_t)(mi * 16 + srw) * N +
                              colR + wc * 64 + (lane & 3) * 16;
        *(s16x8*)dst = w0;
        *(s16x8*)(dst + 8) = w1;
      }
    } else {
      const int orow0 = rowBase + wr * WROWS + lg * 4;
#pragma unroll
      for (int ni = 0; ni < 4; ++ni) {
        int n = ocol0 + ni * 16;
        float bv = bias[n];
#pragma unroll
        for (int mi = 0; mi < M_REP; ++mi) {
#pragma unroll
          for (int r = 0; r < 4; ++r) {
            size_t m = (size_t)(orow0 + mi * 16 + r);
            ((float*)Cout)[m * N + n] = acc[mi][ni][r] + bv;
          }
        }
      }
    }

    if (rep + 1 < REPS) {
      asm volatile("s_waitcnt vmcnt(0)" ::: "memory");
      BAR();
    }
  }

#undef TILE
#undef QUAD
#undef LOAD_A
#undef LOAD_B
#undef STAGE_AU
#undef STAGE_BU
#undef BAR
#undef LG0
}

// ---------------- launch ----------------

extern "C" void kernel_launch(void* const* d_in, const int* in_sizes, int n_in,
                              void* d_out, int out_size, void* d_ws,
                              size_t ws_size, hipStream_t stream) {
  const float* x     = (const float*)d_in[0];
  const float* W1    = (const float*)d_in[1];
  const float* b1    = (const float*)d_in[2];
  const float* theta = (const float*)d_in[3];
  const float* qwr   = (const float*)d_in[4];
  const float* qwi   = (const float*)d_in[5];
  const float* W2    = (const float*)d_in[6];
  const float* b2    = (const float*)d_in[7];
  float* out = (float*)d_out;

  const int M = 4 * 2048;            // 8192
  const int DM = 1024, DF = 4096;

  size_t need = ((size_t)96 << 20) + DF * sizeof(float);
  if (ws_size < need) return;

  char* ws = (char*)d_ws;
  unsigned short* xb   = (unsigned short*)ws;                          // 16 MiB
  unsigned short* w1t  = (unsigned short*)(ws + ((size_t)16 << 20));   //  8 MiB
  unsigned short* w2t  = (unsigned short*)(ws + ((size_t)24 << 20));   //  8 MiB
  unsigned short* actb = (unsigned short*)(ws + ((size_t)32 << 20));   // 64 MiB
  float* c1 = (float*)(ws + ((size_t)96 << 20));

  cvt_f32_bf16<<<2048, 256, 0, stream>>>(x, xb, M * DM / 4);
  transpose_cvt<<<dim3(DF / 32, DM / 32), 256, 0, stream>>>(W1, w1t, DM, DF);
  transpose_cvt<<<dim3(DM / 32, DF / 32), 256, 0, stream>>>(W2, w2t, DF, DM);
  qconst<<<DF / 256, 256, 0, stream>>>(theta, qwr, qwi, c1, DF);

  // GEMM1: 8192x4096, K=1024 -> 256 blocks, each 2 adjacent tn tiles (256^2)
  gemm8<256, 16, 2, true><<<256, 512, 0, stream>>>(
      xb, w1t, b1, theta, c1, (void*)actb, DF, DF / 512);
  // GEMM2: 8192x1024, K=4096 -> 256 blocks (128x256 tile)
  gemm8<128, 64, 1, false><<<256, 512, 0, stream>>>(
      actb, w2t, b2, nullptr, nullptr, (void*)out, DM, DM / 256);
}

// Round 10
// 154.534 us; speedup vs baseline: 1.0915x; 1.0915x over previous
//
#include <hip/hip_runtime.h>

typedef __bf16 bf16x8 __attribute__((ext_vector_type(8)));
typedef short  s16x8  __attribute__((ext_vector_type(8)));
typedef float  f32x4  __attribute__((ext_vector_type(4)));

#define DEVINL __device__ __forceinline__

DEVINL unsigned short f2bf(float f) {
  unsigned int u = __builtin_bit_cast(unsigned int, f);
  u += 0x7fffu + ((u >> 16) & 1u);   // round-to-nearest-even
  return (unsigned short)(u >> 16);
}

DEVINL void async16(const void* g, void* l) {
  __builtin_amdgcn_global_load_lds(
      (const __attribute__((address_space(1))) unsigned int*)g,
      (__attribute__((address_space(3))) unsigned int*)l, 16, 0, 0);
}

// ---------------- fused prep kernel ----------------
// blocks [0,1024)    : x fp32 -> bf16 (grid-stride float4)
// blocks [1024,5120) : W1 [1024][4096] -> w1t [4096][1024] bf16
// blocks [5120,9216) : W2 [4096][1024] -> w2t [1024][4096] bf16
// blocks [9216,9232) : qconst

__global__ __launch_bounds__(256) void prep(
    const float* __restrict__ x, const float* __restrict__ W1,
    const float* __restrict__ W2, const float* __restrict__ theta,
    const float* __restrict__ wre, const float* __restrict__ wim,
    unsigned short* __restrict__ xb, unsigned short* __restrict__ w1t,
    unsigned short* __restrict__ w2t, float* __restrict__ c1) {
  __shared__ unsigned short tile[32][33];
  const int b = blockIdx.x;
  const int tid = threadIdx.x;
  if (b < 1024) {
    int i = b * 256 + tid;
#pragma unroll
    for (int k = 0; k < 8; ++k, i += 262144) {
      float4 v = ((const float4*)x)[i];
      ushort4 o;
      o.x = f2bf(v.x); o.y = f2bf(v.y); o.z = f2bf(v.z); o.w = f2bf(v.w);
      ((ushort4*)xb)[i] = o;
    }
  } else if (b < 5120) {
    int bb = b - 1024;                      // W1: R=1024, C=4096
    int bc = (bb & 127) * 32, br = (bb >> 7) * 32;
    int tx = tid & 31, ty = tid >> 5;
#pragma unroll
    for (int i = 0; i < 32; i += 8)
      tile[ty + i][tx] = f2bf(W1[(size_t)(br + ty + i) * 4096 + (bc + tx)]);
    __syncthreads();
#pragma unroll
    for (int i = 0; i < 32; i += 8)
      w1t[(size_t)(bc + ty + i) * 1024 + (br + tx)] = tile[tx][ty + i];
  } else if (b < 9216) {
    int bb = b - 5120;                      // W2: R=4096, C=1024
    int bc = (bb & 31) * 32, br = (bb >> 5) * 32;
    int tx = tid & 31, ty = tid >> 5;
#pragma unroll
    for (int i = 0; i < 32; i += 8)
      tile[ty + i][tx] = f2bf(W2[(size_t)(br + ty + i) * 1024 + (bc + tx)]);
    __syncthreads();
#pragma unroll
    for (int i = 0; i < 32; i += 8)
      w2t[(size_t)(bc + ty + i) * 4096 + (br + tx)] = tile[tx][ty + i];
  } else {
    int i = (b - 9216) * 256 + tid;         // qconst, n = 4096
    float t = theta[i];
    c1[i] = (cosf(t) * wre[i] + sinf(t) * wim[i]) * wim[i] * 0.1f;
  }
}

// ================= GEMM1: actb = relu(qt(xb @ w1t^T + b1)) =================
// 256x256 tile, BK=64, NT=16, REPS=2 adjacent tn tiles. 8-phase schedule,
// vmcnt ledger verified R8/R9. LDS: 2x64K dbuf + 16K epilogue scratch.

__global__ __launch_bounds__(512, 2) void gemm1k(
    const unsigned short* __restrict__ A,    // xb  [8192][1024]
    const unsigned short* __restrict__ Bt,   // w1t [4096][1024]
    const float* __restrict__ bias,
    const float* __restrict__ theta,
    const float* __restrict__ c1,
    unsigned short* __restrict__ Cout) {     // actb [8192][4096]
  constexpr int K = 1024, N = 4096, NT = 16, REPS = 2;
  constexpr int WROWS = 128, M_REP = 8, MH = 4;
  constexpr int ABYTES = 32768, AH = 16384, AL = 2;
  constexpr int BUFSZ = 65536;
  constexpr int nTilesN = 8;                 // 4096 / 512

  __shared__ __align__(16) char lds[2 * BUFSZ + 16384];

  int nwg = gridDim.x;
  int wg = blockIdx.x;
  int sw = (wg & 7) * (nwg >> 3) + (wg >> 3);
  int rowBase = (sw / nTilesN) * 256;
  int colBase = (sw % nTilesN) * 512;

  const int t = threadIdx.x;
  const int lane = t & 63;
  const int wid = t >> 6;
  const int wr = wid >> 2, wc = wid & 3;
  const int lr = lane & 15;
  const int lg = lane >> 4;
  const int r7 = lane & 7;

  const int srow = t >> 3;
  const int scolB = ((t & 7) * 16) ^ ((srow & 7) << 4);
  const unsigned short* aSrcB = A  + (size_t)(rowBase + srow) * K + (scolB >> 1);
  const unsigned short* bSrcB = Bt + (size_t)(colBase + srow) * K + (scolB >> 1);

  const int aRd = (wr * WROWS + lr) * 128 + ((lg ^ r7) << 4);
  const int bRd = ABYTES + (wc * 64 + lr) * 128 + ((lg ^ r7) << 4);

#define STAGE_AU(S, U, P) do {                                              \
    _Pragma("unroll") for (int j = 0; j < AL; ++j)                          \
      async16(aSrcB + ((size_t)((U) * WROWS + j * 64) * K + (size_t)(S) * 64),\
              &lds[(P) * BUFSZ + (U) * AH + j * 8192 + t * 16]);            \
  } while (0)
#define STAGE_BU(SRC, S, U, P) do {                                         \
    _Pragma("unroll") for (int j = 0; j < 2; ++j)                           \
      async16((SRC) + ((size_t)((U) * 128 + j * 64) * K + (size_t)(S) * 64),\
              &lds[(P) * BUFSZ + ABYTES + (U) * 16384 + j * 8192 + t * 16]);\
  } while (0)
#define LOAD_A(MHh, P)                                                      \
  _Pragma("unroll") for (int mi = 0; mi < MH; ++mi)                         \
  _Pragma("unroll") for (int ks = 0; ks < 2; ++ks)                          \
    a[mi][ks] = __builtin_bit_cast(bf16x8, *(const s16x8*)&lds[             \
        (P) * BUFSZ + ((aRd + ((MHh) * MH + mi) * 2048) ^ (ks << 6))])
#define LOAD_B(NHh, P)                                                      \
  _Pragma("unroll") for (int nn = 0; nn < 2; ++nn)                          \
  _Pragma("unroll") for (int ks = 0; ks < 2; ++ks)                          \
    b[(NHh) * 2 + nn][ks] = __builtin_bit_cast(bf16x8, *(const s16x8*)&lds[ \
        (P) * BUFSZ + ((bRd + ((NHh) * 2 + nn) * 2048) ^ (ks << 6))])
#define QUAD(MHh, NHh)                                                      \
  __builtin_amdgcn_s_setprio(1);                                            \
  _Pragma("unroll") for (int mi = 0; mi < MH; ++mi)                         \
  _Pragma("unroll") for (int nn = 0; nn < 2; ++nn)                          \
  _Pragma("unroll") for (int ks = 0; ks < 2; ++ks)                          \
    acc[(MHh) * MH + mi][(NHh) * 2 + nn] =                                  \
        __builtin_amdgcn_mfma_f32_16x16x32_bf16(                            \
            a[mi][ks], b[(NHh) * 2 + nn][ks],                               \
            acc[(MHh) * MH + mi][(NHh) * 2 + nn], 0, 0, 0);                 \
  __builtin_amdgcn_s_setprio(0)
#define BAR() __builtin_amdgcn_s_barrier()
#define LG0() asm volatile("s_waitcnt lgkmcnt(0)" ::: "memory")
#define TILE(T, P) do {                                                     \
    LOAD_A(0, P); LOAD_B(0, P);                                             \
    if ((T) + 1 < NT) STAGE_AU((T) + 1, 0, (P) ^ 1);                        \
    asm volatile("s_waitcnt lgkmcnt(8)" ::: "memory");                      \
    BAR(); LG0(); QUAD(0, 0); BAR();                                        \
    LOAD_B(1, P);                                                           \
    if ((T) + 1 < NT) STAGE_AU((T) + 1, 1, (P) ^ 1);                        \
    BAR(); LG0(); QUAD(0, 1); BAR();                                        \
    LOAD_A(1, P);                                                           \
    if ((T) + 2 < NT) STAGE_BU(bSrcR, (T) + 2, 0, P);                       \
    BAR(); LG0(); QUAD(1, 1); BAR();                                        \
    if ((T) + 2 < NT) STAGE_BU(bSrcR, (T) + 2, 1, P);                       \
    BAR(); QUAD(1, 0);                                                      \
    if ((T) + 2 < NT) {                                                     \
      asm volatile("s_waitcnt vmcnt(4)" ::: "memory");                      \
    } else if ((T) + 1 < NT) {                                              \
      asm volatile("s_waitcnt vmcnt(0)" ::: "memory");                      \
    }                                                                       \
    BAR();                                                                  \
  } while (0)

  STAGE_AU(0, 0, 0); STAGE_AU(0, 1, 0);
  STAGE_BU(bSrcB, 0, 0, 0); STAGE_BU(bSrcB, 0, 1, 0);
  STAGE_BU(bSrcB, 1, 0, 1); STAGE_BU(bSrcB, 1, 1, 1);
  asm volatile("s_waitcnt vmcnt(4)" ::: "memory");
  BAR();

  for (int rep = 0; rep < REPS; ++rep) {
    const unsigned short* bSrcR = bSrcB + (size_t)rep * 256 * K;
    f32x4 acc[M_REP][4] = {};
    bf16x8 a[MH][2], b[4][2];

    for (int T = 0; T < NT; T += 2) {
      TILE(T, 0);
      TILE(T + 1, 1);
    }

    if (rep + 1 < REPS) {
      const unsigned short* bSrcN = bSrcB + (size_t)(rep + 1) * 256 * K;
      STAGE_AU(0, 0, 0); STAGE_AU(0, 1, 0);
      STAGE_BU(bSrcN, 0, 0, 0); STAGE_BU(bSrcN, 0, 1, 0);
      STAGE_BU(bSrcN, 1, 0, 1); STAGE_BU(bSrcN, 1, 1, 1);
    }

    // ---- fused epilogue (bias + quantum + relu), full-line bf16 stores ----
    const int colR = colBase + rep * 256;
    const int ocol0 = colR + wc * 64 + lr;
    float bvv[4], thv[4], ccv[4];
#pragma unroll
    for (int ni = 0; ni < 4; ++ni) {
      int n = ocol0 + ni * 16;
      bvv[ni] = bias[n]; thv[ni] = theta[n]; ccv[ni] = c1[n];
    }
    const int SB = 2 * BUFSZ + wid * 2048;
    const size_t growB = (size_t)(rowBase + wr * WROWS) * N;
    const int rd = lane >> 3;                // 0..7
    const int bo = (lane & 7) * 16;          // 0..112
#pragma unroll
    for (int mi = 0; mi < M_REP; ++mi) {
#pragma unroll
      for (int ni = 0; ni < 4; ++ni) {
#pragma unroll
        for (int r = 0; r < 4; ++r) {
          int row16 = lg * 4 + r;
          float h = acc[mi][ni][r] + bvv[ni];
          float q = h + ccv[ni] * __sinf(thv[ni] + 0.1f * h);
          unsigned short v = f2bf(fmaxf(q, 0.f));
          int ad = SB + row16 * 128 +
                   (((ni * 16 + lr) * 2) ^ ((row16 & 7) << 4));
          *(unsigned short*)&lds[ad] = v;
        }
      }
      s16x8 w0 = *(const s16x8*)&lds[SB + rd * 128 + (bo ^ ((rd & 7) << 4))];
      s16x8 w1 = *(const s16x8*)&lds[SB + (rd + 8) * 128 +
                                     (bo ^ ((rd & 7) << 4))];
      unsigned short* dst = Cout + growB + (size_t)(mi * 16 + rd) * N +
                            colR + wc * 64 + (lane & 7) * 8;
      *(s16x8*)dst = w0;
      *(s16x8*)(dst + (size_t)8 * N) = w1;   // rows rd and rd+8
    }

    if (rep + 1 < REPS) {
      asm volatile("s_waitcnt vmcnt(0)" ::: "memory");
      BAR();
    }
  }
#undef TILE
#undef QUAD
#undef LOAD_A
#undef LOAD_B
#undef STAGE_AU
#undef STAGE_BU
#undef BAR
#undef LG0
}

// ================= GEMM2: out = actb @ w2t^T + b2 (fp32) =================
// 128x256 tile, BK=64, NT=64 — R8 loop structure verbatim; new full-line
// fp32 epilogue via per-wave 4KB LDS scratch.

__global__ __launch_bounds__(512, 2) void gemm2k(
    const unsigned short* __restrict__ A,    // actb [8192][4096]
    const unsigned short* __restrict__ Bt,   // w2t  [1024][4096]
    const float* __restrict__ bias,
    float* __restrict__ Cout) {              // out [8192][1024]
  constexpr int K = 4096, N = 1024, NT = 64;
  constexpr int WROWS = 64, M_REP = 4, MH = 2;
  constexpr int ABYTES = 16384, AH = 8192, AL = 1;
  constexpr int BUFSZ = 49152;
  constexpr int nTilesN = 4;

  __shared__ __align__(16) char lds[2 * BUFSZ + 32768];

  int nwg = gridDim.x;
  int wg = blockIdx.x;
  int sw = (wg & 7) * (nwg >> 3) + (wg >> 3);
  int rowBase = (sw / nTilesN) * 128;
  int colBase = (sw % nTilesN) * 256;

  const int t = threadIdx.x;
  const int lane = t & 63;
  const int wid = t >> 6;
  const int wr = wid >> 2, wc = wid & 3;
  const int lr = lane & 15;
  const int lg = lane >> 4;
  const int r7 = lane & 7;

  const int srow = t >> 3;
  const int scolB = ((t & 7) * 16) ^ ((srow & 7) << 4);
  const unsigned short* aSrcB = A  + (size_t)(rowBase + srow) * K + (scolB >> 1);
  const unsigned short* bSrcB = Bt + (size_t)(colBase + srow) * K + (scolB >> 1);

  const int aRd = (wr * WROWS + lr) * 128 + ((lg ^ r7) << 4);
  const int bRd = ABYTES + (wc * 64 + lr) * 128 + ((lg ^ r7) << 4);

  f32x4 acc[M_REP][4] = {};
  bf16x8 a[MH][2], b[4][2];

#define STAGE_AU(S, U, P) do {                                              \
    _Pragma("unroll") for (int j = 0; j < AL; ++j)                          \
      async16(aSrcB + ((size_t)((U) * WROWS + j * 64) * K + (size_t)(S) * 64),\
              &lds[(P) * BUFSZ + (U) * AH + j * 8192 + t * 16]);            \
  } while (0)
#define STAGE_BU(S, U, P) do {                                              \
    _Pragma("unroll") for (int j = 0; j < 2; ++j)                           \
      async16(bSrcB + ((size_t)((U) * 128 + j * 64) * K + (size_t)(S) * 64),\
              &lds[(P) * BUFSZ + ABYTES + (U) * 16384 + j * 8192 + t * 16]);\
  } while (0)
#define LOAD_A(MHh, P)                                                      \
  _Pragma("unroll") for (int mi = 0; mi < MH; ++mi)                         \
  _Pragma("unroll") for (int ks = 0; ks < 2; ++ks)                          \
    a[mi][ks] = __builtin_bit_cast(bf16x8, *(const s16x8*)&lds[             \
        (P) * BUFSZ + ((aRd + ((MHh) * MH + mi) * 2048) ^ (ks << 6))])
#define LOAD_B(NHh, P)                                                      \
  _Pragma("unroll") for (int nn = 0; nn < 2; ++nn)                          \
  _Pragma("unroll") for (int ks = 0; ks < 2; ++ks)                          \
    b[(NHh) * 2 + nn][ks] = __builtin_bit_cast(bf16x8, *(const s16x8*)&lds[ \
        (P) * BUFSZ + ((bRd + ((NHh) * 2 + nn) * 2048) ^ (ks << 6))])
#define QUAD(MHh, NHh)                                                      \
  __builtin_amdgcn_s_setprio(1);                                            \
  _Pragma("unroll") for (int mi = 0; mi < MH; ++mi)                         \
  _Pragma("unroll") for (int nn = 0; nn < 2; ++nn)                          \
  _Pragma("unroll") for (int ks = 0; ks < 2; ++ks)                          \
    acc[(MHh) * MH + mi][(NHh) * 2 + nn] =                                  \
        __builtin_amdgcn_mfma_f32_16x16x32_bf16(                            \
            a[mi][ks], b[(NHh) * 2 + nn][ks],                               \
            acc[(MHh) * MH + mi][(NHh) * 2 + nn], 0, 0, 0);                 \
  __builtin_amdgcn_s_setprio(0)
#define BAR() __builtin_amdgcn_s_barrier()
#define LG0() asm volatile("s_waitcnt lgkmcnt(0)" ::: "memory")
#define TILE(T, P) do {                                                     \
    LOAD_A(0, P); LOAD_B(0, P);                                             \
    if ((T) + 1 < NT) STAGE_AU((T) + 1, 0, (P) ^ 1);                        \
    BAR(); LG0(); QUAD(0, 0); BAR();                                        \
    LOAD_B(1, P);                                                           \
    if ((T) + 1 < NT) STAGE_AU((T) + 1, 1, (P) ^ 1);                        \
    BAR(); LG0(); QUAD(0, 1); BAR();                                        \
    LOAD_A(1, P);                                                           \
    if ((T) + 2 < NT) STAGE_BU((T) + 2, 0, P);                              \
    BAR(); LG0(); QUAD(1, 1); BAR();                                        \
    if ((T) + 2 < NT) STAGE_BU((T) + 2, 1, P);                              \
    BAR(); QUAD(1, 0);                                                      \
    if ((T) + 2 < NT) {                                                     \
      asm volatile("s_waitcnt vmcnt(4)" ::: "memory");                      \
    } else if ((T) + 1 < NT) {                                              \
      asm volatile("s_waitcnt vmcnt(0)" ::: "memory");                      \
    }                                                                       \
    BAR();                                                                  \
  } while (0)

  STAGE_AU(0, 0, 0); STAGE_AU(0, 1, 0);
  STAGE_BU(0, 0, 0); STAGE_BU(0, 1, 0);
  STAGE_BU(1, 0, 1); STAGE_BU(1, 1, 1);
  asm volatile("s_waitcnt vmcnt(4)" ::: "memory");
  BAR();

  for (int T = 0; T < NT; T += 2) {
    TILE(T, 0);
    TILE(T + 1, 1);
  }
#undef TILE
#undef QUAD
#undef LOAD_A
#undef LOAD_B
#undef STAGE_AU
#undef STAGE_BU
#undef BAR
#undef LG0

  // ---- full-line fp32 epilogue via per-wave 4KB scratch ----
  const int ocol0 = colBase + wc * 64 + lr;
  float bvv[4];
#pragma unroll
  for (int ni = 0; ni < 4; ++ni) bvv[ni] = bias[ocol0 + ni * 16];
  const int SB = 2 * BUFSZ + wid * 4096;
  const int orowB = rowBase + wr * WROWS;
  const int rd = lane >> 3;                  // 0..7
  const int bo = (lane & 7) * 16;            // 0..112
#pragma unroll
  for (int mi = 0; mi < M_REP; ++mi) {
#pragma unroll
    for (int ni = 0; ni < 4; ++ni) {
#pragma unroll
      for (int r = 0; r < 4; ++r) {
        int row16 = lg * 4 + r;
        int ad = SB + row16 * 256 +
                 (((ni * 16 + lr) * 4) ^ ((row16 & 7) << 4));
        *(float*)&lds[ad] = acc[mi][ni][r] + bvv[ni];
      }
    }
    f32x4 v00 = *(const f32x4*)&lds[SB + rd * 256 + (bo ^ ((rd & 7) << 4))];
    f32x4 v01 = *(const f32x4*)&lds[SB + rd * 256 +
                                    ((bo + 128) ^ ((rd & 7) << 4))];
    f32x4 v10 = *(const f32x4*)&lds[SB + (rd + 8) * 256 +
                                    (bo ^ ((rd & 7) << 4))];
    f32x4 v11 = *(const f32x4*)&lds[SB + (rd + 8) * 256 +
                                    ((bo + 128) ^ ((rd & 7) << 4))];
    float* dst0 = Cout + (size_t)(orowB + mi * 16 + rd) * N +
                  colBase + wc * 64 + (lane & 7) * 4;
    *(f32x4*)dst0 = v00;
    *(f32x4*)(dst0 + 32) = v01;
    float* dst1 = dst0 + (size_t)8 * N;
    *(f32x4*)dst1 = v10;
    *(f32x4*)(dst1 + 32) = v11;
  }
}

// ---------------- launch ----------------

extern "C" void kernel_launch(void* const* d_in, const int* in_sizes, int n_in,
                              void* d_out, int out_size, void* d_ws,
                              size_t ws_size, hipStream_t stream) {
  const float* x     = (const float*)d_in[0];
  const float* W1    = (const float*)d_in[1];
  const float* b1    = (const float*)d_in[2];
  const float* theta = (const float*)d_in[3];
  const float* qwr   = (const float*)d_in[4];
  const float* qwi   = (const float*)d_in[5];
  const float* W2    = (const float*)d_in[6];
  const float* b2    = (const float*)d_in[7];
  float* out = (float*)d_out;

  const int DF = 4096;
  size_t need = ((size_t)96 << 20) + DF * sizeof(float);
  if (ws_size < need) return;

  char* ws = (char*)d_ws;
  unsigned short* xb   = (unsigned short*)ws;                          // 16 MiB
  unsigned short* w1t  = (unsigned short*)(ws + ((size_t)16 << 20));   //  8 MiB
  unsigned short* w2t  = (unsigned short*)(ws + ((size_t)24 << 20));   //  8 MiB
  unsigned short* actb = (unsigned short*)(ws + ((size_t)32 << 20));   // 64 MiB
  float* c1 = (float*)(ws + ((size_t)96 << 20));

  prep<<<9232, 256, 0, stream>>>(x, W1, W2, theta, qwr, qwi,
                                 xb, w1t, w2t, c1);
  gemm1k<<<256, 512, 0, stream>>>(xb, w1t, b1, theta, c1, actb);
  gemm2k<<<256, 512, 0, stream>>>(actb, w2t, b2, out);
}